// Round 1
// baseline (92.548 us; speedup 1.0000x reference)
//
#include <hip/hip_runtime.h>

__global__ void returning_rate_kernel(const float* __restrict__ pred,
                                      const float* __restrict__ mask,
                                      float* __restrict__ out, int B) {
    int idx = blockIdx.x * blockDim.x + threadIdx.x;
    int stride = gridDim.x * blockDim.x;
    for (int s = idx; s < B; s += stride) {
        const float* pr = pred + (size_t)s * 25;
        const float* mk = mask + (size_t)s * 25;

        // pred[i][j] -> flat i*5+j
        float p40 = pr[20], p41 = pr[21], p42 = pr[22], p43 = pr[23], p44 = pr[24];
        float p31 = pr[16], p32 = pr[17], p33 = pr[18], p34 = pr[19];
        float p22 = pr[12], p23 = pr[13], p24 = pr[14];
        float p13 = pr[8],  p14 = pr[9];
        float p04 = pr[4];
        float m31 = mk[16], m22 = mk[12], m13 = mk[8], m04 = mk[4];

        // p1: mask multiplies only the LAST product term (Python precedence)
        float p1_1 = p40 * p41 * m31;
        float p1_2 = p40 * p42 + p31 * p32 * m22;
        float p1_3 = p40 * p43 + p31 * p33 + p22 * p23 * m13;
        float p1_4 = p40 * p44 + p31 * p34 + p22 * p24 + p13 * p14 * m04;

        // p2: complement chain
        float q40 = 1.f - p40, q31 = 1.f - p31, q22 = 1.f - p22, q13 = 1.f - p13;
        float p2_1 = q31 * (1.f - q40) * m31;
        float p2_2 = q22 * (1.f - q40 * q31) * m22;
        float p2_3 = q13 * (1.f - q40 * q31 * q22) * m13;
        float p2_4 = (1.f - p04) * (1.f - q40 * q31 * q22 * q13) * m04;

        float* o1 = out + (size_t)s * 5;
        o1[0] = 0.f; o1[1] = p1_1; o1[2] = p1_2; o1[3] = p1_3; o1[4] = p1_4;
        float* o2 = out + (size_t)B * 5 + (size_t)s * 5;
        o2[0] = 0.f; o2[1] = p2_1; o2[2] = p2_2; o2[3] = p2_3; o2[4] = p2_4;
    }
}

extern "C" void kernel_launch(void* const* d_in, const int* in_sizes, int n_in,
                              void* d_out, int out_size, void* d_ws, size_t ws_size,
                              hipStream_t stream) {
    const float* pred = (const float*)d_in[0];
    const float* mask = (const float*)d_in[1];
    float* out = (float*)d_out;
    int B = in_sizes[0] / 25;

    const int block = 256;
    int blocks = (B + block - 1) / block;
    if (blocks > 8192) blocks = 8192;
    returning_rate_kernel<<<blocks, block, 0, stream>>>(pred, mask, out, B);
}